// Round 9
// baseline (301.953 us; speedup 1.0000x reference)
//
#include <hip/hip_runtime.h>
#include <math.h>

// HGT layer, MI355X. f32 inputs/outputs; bf16 intermediates (f32 accumulation).
// Round 9: GEMM staging via __builtin_amdgcn_global_load_lds (width=16) for
// B tiles (both GEMMs) and gemm_ln's A tile. LDS images are unpadded pitch-128
// with XOR-swizzled 8-short groups (g ^= row&7); Wfb and gbuf are written
// PRE-SWIZZLED at their source (fuse_weights / gather_fused). 128-row tiles.
// Pipeline:
//  1) fuse_weights: fold a_rel/m_rel (+ p_rel/4 for khat) into weights
//     (bf16, swizzled layout); zero cnt
//  2) qkv_fill: blocks [0,Gg): QKV MFMA gemm (A staged manually f32->bf16
//     swizzled; B via global_load_lds); blocks [Gg,..): edge-bucket fill
//  3) gather_fused: per-dst wave, 4 edges in flight; writes gbuf swizzled
//  4) gemm_ln: A(gbuf)+B via global_load_lds; skip/relu/LayerNorm fused

#define EB_STRIDE 40   // max in-degree bucket; Poisson(10): P(>=40) ~ 1e-13

typedef __attribute__((ext_vector_type(8))) short short8;
typedef __attribute__((ext_vector_type(4))) float floatx4;

__device__ __forceinline__ float bf2f(unsigned int bits16) {
  union { unsigned int i; float f; } u; u.i = bits16 << 16; return u.f;
}
__device__ __forceinline__ float bf2f_hi(unsigned int u) {
  union { unsigned int i; float f; } v; v.i = u & 0xffff0000u; return v.f;
}
__device__ __forceinline__ unsigned int f2bf(float f) {
  union { float ff; unsigned int i; } u; u.ff = f;
  unsigned int x = u.i;
  x += 0x7fffu + ((x >> 16) & 1u);
  return x >> 16;
}

// async global->LDS DMA, 16B/lane: lds base wave-uniform, g per-lane
__device__ __forceinline__ void gld16(void* lds, const void* g) {
  __builtin_amdgcn_global_load_lds(
      (const __attribute__((address_space(1))) void*)g,
      (__attribute__((address_space(3))) void*)lds, 16, 0, 0);
}

// swizzled fragment read: 8 shorts of (row, k-group g), image pitch 128
__device__ __forceinline__ short8 lds_frag(const unsigned short* base, int row, int g) {
  return *(const short8*)&base[row * 128 + ((g ^ (row & 7)) << 3)];
}

// ---------------------------------------------------------------- fuse weights (+cnt zero)
// Wfb: [t][m] 128x128 bf16 in SWIZZLED image layout; m: 0=q, 1=khat, 2=vhat, 3=a
__global__ void fuse_weights(
    const float* __restrict__ k_w, const float* __restrict__ k_b,
    const float* __restrict__ q_w, const float* __restrict__ q_b,
    const float* __restrict__ v_w, const float* __restrict__ v_b,
    const float* __restrict__ a_w, const float* __restrict__ a_b,
    const float* __restrict__ a_rel, const float* __restrict__ m_rel,
    const float* __restrict__ p_rel,
    unsigned short* __restrict__ Wfb, float* __restrict__ Bf,
    int* __restrict__ cnt, int nC)
{
  int tid = blockIdx.x * 256 + threadIdx.x;
  if (tid < nC) cnt[tid] = 0;
  if (tid >= 2 * 4 * 128 * 128) return;
  int t   = tid >> 16;
  int rem = tid & 65535;
  int m   = rem >> 14;
  int o   = (rem >> 7) & 127;
  int i   = rem & 127;
  float w, bias;
  if (m == 0) {
    w    = q_w[t * 16384 + o * 128 + i];
    bias = q_b[t * 128 + o];
  } else if (m == 3) {
    w    = a_w[t * 16384 + o * 128 + i];
    bias = a_b[t * 128 + o];
  } else {
    const float* bw  = (m == 1) ? k_w : v_w;
    const float* bb  = (m == 1) ? k_b : v_b;
    const float* rel = (m == 1) ? a_rel : m_rel;  // edge type e == source type t
    int h = o >> 4, eo = o & 15;
    float s = 0.f, sb = 0.f;
    #pragma unroll
    for (int d = 0; d < 16; ++d) {
      float r = rel[t * 2048 + h * 256 + d * 16 + eo];
      s  += bw[t * 16384 + (h * 16 + d) * 128 + i] * r;
      sb += bb[t * 128 + h * 16 + d] * r;
    }
    if (m == 1) {               // fold p_rel / sqrt(D) into khat
      float sc = p_rel[t * 8 + h] * 0.25f;
      s *= sc; sb *= sc;
    }
    w = s; bias = sb;
  }
  // swizzled element position: group (i>>3) -> (i>>3) ^ (o&7)
  int sidx = ((tid >> 7) << 7) | ((((i >> 3) ^ (o & 7)) << 3) | (i & 7));
  Wfb[sidx] = (unsigned short)f2bf(w);
  if (i == 0) Bf[t * 512 + m * 128 + o] = bias;
}

// ---------------------------------------------------------------- QKV gemm + edge fill
// blocks [0,Gg): gemm, 128-row tile (t = b&1, m0 = (b>>1)*128);
// blocks [Gg,+Fb): fill (e = f&1, 256 edges per block).
__global__ __launch_bounds__(256) void qkv_fill(
    const float* __restrict__ x, const unsigned short* __restrict__ Wfb,
    const float* __restrict__ Bf, unsigned short* __restrict__ qbuf,
    unsigned short* __restrict__ kvbuf,
    const int* __restrict__ ei, int* __restrict__ cnt, int* __restrict__ ebuf,
    int Nn, int E, int Gg)
{
  __shared__ alignas(16) unsigned short Als[16384];   // 128 rows x 128 (swizzled)
  __shared__ alignas(16) unsigned short Bls[16384];
  const int b = blockIdx.x;
  const int tid = threadIdx.x;

  if (b >= Gg) {   // ---------------- edge-bucket fill portion
    int f = b - Gg;
    int e = f & 1;
    int i = (f >> 1) * 256 + tid;
    if (i < E) {
      int src = ei[(size_t)e * 2 * E + i];
      int dst = ei[(size_t)e * 2 * E + E + i];
      int bk = (1 - e) * Nn + dst;        // dst type dt = 1-e
      int pos = atomicAdd(&cnt[bk], 1);
      if (pos < EB_STRIDE) ebuf[(size_t)bk * EB_STRIDE + pos] = src;
    }
    return;
  }

  // ---------------- gemm portion
  const int t = b & 1;
  const int m0 = (b >> 1) * 128;
  const int lane = tid & 63, w = tid >> 6;
  const int col = lane & 15, quad = lane >> 4;
  const int morder[3] = {1, 2, 0};

  {  // stage A tile (f32 -> bf16, swizzled groups)
    int r = tid & 127, h = tid >> 7;     // h: half of the 16 groups
    int gn = m0 + r;
    if (gn < Nn) {
      const float* xrow = x + ((size_t)t * Nn + gn) * 128;
      #pragma unroll
      for (int j = 0; j < 8; ++j) {
        int g = h * 8 + j;
        float4 f0 = *(const float4*)(xrow + g * 8);
        float4 f1 = *(const float4*)(xrow + g * 8 + 4);
        uint4 u;
        u.x = f2bf(f0.x) | (f2bf(f0.y) << 16);
        u.y = f2bf(f0.z) | (f2bf(f0.w) << 16);
        u.z = f2bf(f1.x) | (f2bf(f1.y) << 16);
        u.w = f2bf(f1.z) | (f2bf(f1.w) << 16);
        *(uint4*)&Als[r * 128 + ((g ^ (r & 7)) << 3)] = u;
      }
    } else {
      uint4 z = make_uint4(0, 0, 0, 0);
      #pragma unroll
      for (int j = 0; j < 8; ++j) {
        int g = h * 8 + j;
        *(uint4*)&Als[r * 128 + ((g ^ (r & 7)) << 3)] = z;
      }
    }
  }

  float acc_k[2][8][4];   // stashed biased khat
  float bias_n[8];

  for (int mi_ = 0; mi_ < 3; ++mi_) {
    int m = morder[mi_];
    __syncthreads();   // A visible (first iter); prior B reads done before DMA overwrite
    {  // stage B_m via async DMA (Wfb already in swizzled image layout)
      const unsigned short* Bm = Wfb + (((size_t)(t * 4 + m)) << 14);
      #pragma unroll
      for (int i = 0; i < 8; ++i) {
        int cc = w * 8 + i;              // 1 KB chunk
        gld16(&Bls[cc * 512], Bm + cc * 512 + lane * 8);
      }
    }
    __syncthreads();

    floatx4 acc[2][8];
    #pragma unroll
    for (int mi = 0; mi < 2; ++mi)
      #pragma unroll
      for (int ni = 0; ni < 8; ++ni) acc[mi][ni] = (floatx4)(0.f);

    #pragma unroll
    for (int k0 = 0; k0 < 128; k0 += 32) {
      int gk = (k0 >> 3) + quad;
      short8 a0 = lds_frag(Als, w * 32 + col, gk);
      short8 a1 = lds_frag(Als, w * 32 + 16 + col, gk);
      #pragma unroll
      for (int ni = 0; ni < 8; ++ni) {
        short8 bf_ = lds_frag(Bls, ni * 16 + col, gk);
        acc[0][ni] = __builtin_amdgcn_mfma_f32_16x16x32_bf16(a0, bf_, acc[0][ni], 0, 0, 0);
        acc[1][ni] = __builtin_amdgcn_mfma_f32_16x16x32_bf16(a1, bf_, acc[1][ni], 0, 0, 0);
      }
    }

    const float* Bv = Bf + t * 512 + m * 128;
    #pragma unroll
    for (int ni = 0; ni < 8; ++ni) bias_n[ni] = Bv[ni * 16 + col];

    if (m == 1) {
      #pragma unroll
      for (int mi = 0; mi < 2; ++mi)
        #pragma unroll
        for (int ni = 0; ni < 8; ++ni)
          #pragma unroll
          for (int reg = 0; reg < 4; ++reg)
            acc_k[mi][ni][reg] = acc[mi][ni][reg] + bias_n[ni];
    } else if (m == 2) {
      // packed (khat, vhat) uint pairs: quad covers full 64B sectors
      unsigned int* kvp = (unsigned int*)kvbuf + ((size_t)t * Nn) * 128;
      #pragma unroll
      for (int mi = 0; mi < 2; ++mi)
        #pragma unroll
        for (int reg = 0; reg < 4; ++reg) {
          int row = m0 + w * 32 + mi * 16 + quad * 4 + reg;
          if (row >= Nn) continue;
          unsigned int* cp = kvp + (size_t)row * 128 + col;
          #pragma unroll
          for (int ni = 0; ni < 8; ++ni) {
            unsigned int kbits = f2bf(acc_k[mi][ni][reg]);
            unsigned int vbits = f2bf(acc[mi][ni][reg] + bias_n[ni]);
            cp[ni * 16] = (vbits << 16) | kbits;   // kv[2c]=khat, kv[2c+1]=vhat
          }
        }
    } else {
      #pragma unroll
      for (int mi = 0; mi < 2; ++mi)
        #pragma unroll
        for (int reg = 0; reg < 4; ++reg) {
          int row = m0 + w * 32 + mi * 16 + quad * 4 + reg;
          if (row >= Nn) continue;
          unsigned short* cp = qbuf + ((size_t)t * Nn + row) * 128 + col;
          #pragma unroll
          for (int ni = 0; ni < 8; ++ni)
            cp[ni * 16] = (unsigned short)f2bf(acc[mi][ni][reg] + bias_n[ni]);
        }
    }
  }
}

// ---------------------------------------------------------------- fused gather
// one wave per dst node; 4 edges in flight (group g = lane>>4 owns edge j0+g,
// lane gl = lane&15 owns channels [8gl, 8gl+8)). gbuf written SWIZZLED.
__global__ __launch_bounds__(256) void gather_fused(
    const unsigned short* __restrict__ qbuf, const unsigned short* __restrict__ kvbuf,
    const int* __restrict__ cnt, const int* __restrict__ ebuf,
    unsigned short* __restrict__ gbuf, int N)
{
  int wid = (blockIdx.x * 256 + threadIdx.x) >> 6;   // bucket = dt*N + dst
  int l = threadIdx.x & 63;
  if (wid >= 2 * N) return;
  int dt = (wid >= N) ? 1 : 0;
  int e  = 1 - dt;                                   // source type
  int deg = cnt[wid]; if (deg > EB_STRIDE) deg = EB_STRIDE;
  int g = l >> 4, gl = l & 15;

  uint4 qr = *(const uint4*)(qbuf + (size_t)wid * 128 + 8 * gl);
  float qv[8];
  qv[0] = bf2f(qr.x & 0xffffu); qv[1] = bf2f(qr.x >> 16);
  qv[2] = bf2f(qr.y & 0xffffu); qv[3] = bf2f(qr.y >> 16);
  qv[4] = bf2f(qr.z & 0xffffu); qv[5] = bf2f(qr.z >> 16);
  qv[6] = bf2f(qr.w & 0xffffu); qv[7] = bf2f(qr.w >> 16);

  const unsigned short* kvbase = kvbuf + ((size_t)e * N) * 256;
  const int* eb = ebuf + (size_t)wid * EB_STRIDE;
  int mysrc = (l < deg) ? eb[l] : 0;

  float acc[8];
  #pragma unroll
  for (int c = 0; c < 8; ++c) acc[c] = 0.f;
  float den = 0.f;

  for (int j0 = 0; j0 < deg; j0 += 4) {
    int j = j0 + g;
    bool valid = j < deg;
    int src = __shfl(mysrc, valid ? j : 0, 64);
    const unsigned short* kv = kvbase + (size_t)src * 256 + 16 * gl;
    uint4 a = *(const uint4*)kv;        // channels 8gl+0..3 as (khat, vhat) pairs
    uint4 b = *(const uint4*)(kv + 8);  // channels 8gl+4..7
    float p;
    p = qv[0] * bf2f(a.x & 0xffffu);
    p = fmaf(qv[1], bf2f(a.y & 0xffffu), p);
    p = fmaf(qv[2], bf2f(a.z & 0xffffu), p);
    p = fmaf(qv[3], bf2f(a.w & 0xffffu), p);
    p = fmaf(qv[4], bf2f(b.x & 0xffffu), p);
    p = fmaf(qv[5], bf2f(b.y & 0xffffu), p);
    p = fmaf(qv[6], bf2f(b.z & 0xffffu), p);
    p = fmaf(qv[7], bf2f(b.w & 0xffffu), p);
    float pt = p + __shfl_xor(p, 1, 64);   // partner lane completes the 16-ch head dot
    float ex = valid ? __expf(pt) : 0.f;   // alpha scale folded into khat weights
    den += ex;
    acc[0] = fmaf(ex, bf2f_hi(a.x), acc[0]);
    acc[1] = fmaf(ex, bf2f_hi(a.y), acc[1]);
    acc[2] = fmaf(ex, bf2f_hi(a.z), acc[2]);
    acc[3] = fmaf(ex, bf2f_hi(a.w), acc[3]);
    acc[4] = fmaf(ex, bf2f_hi(b.x), acc[4]);
    acc[5] = fmaf(ex, bf2f_hi(b.y), acc[5]);
    acc[6] = fmaf(ex, bf2f_hi(b.z), acc[6]);
    acc[7] = fmaf(ex, bf2f_hi(b.w), acc[7]);
  }

  #pragma unroll
  for (int off = 16; off < 64; off <<= 1) {
    #pragma unroll
    for (int c = 0; c < 8; ++c) acc[c] += __shfl_xor(acc[c], off, 64);
    den += __shfl_xor(den, off, 64);
  }

  if (g == 0) {
    float rden = 1.f / (den + 1e-16f);
    unsigned int r[8];
    #pragma unroll
    for (int c = 0; c < 8; ++c) {
      float gg = acc[c] * rden;
      r[c] = f2bf(0.5f * gg * (1.f + erff(gg * 0.70710678118654752f)));
    }
    uint4 u;
    u.x = r[0] | (r[1] << 16); u.y = r[2] | (r[3] << 16);
    u.z = r[4] | (r[5] << 16); u.w = r[6] | (r[7] << 16);
    // swizzled group position (N % 8 == 0, tiles 128-aligned -> key = local row & 7)
    *(uint4*)(gbuf + (size_t)wid * 128 + ((gl ^ (wid & 7)) << 3)) = u;
  }
}

// ---------------------------------------------------------------- out GEMM + LN
// 128-row tile. A (gbuf, pre-swizzled) and B via global_load_lds.
__global__ __launch_bounds__(256) void gemm_ln(
    const unsigned short* __restrict__ gbuf, const unsigned short* __restrict__ Wfb,
    const float* __restrict__ Bf, const float* __restrict__ x,
    const float* __restrict__ skip, const float* __restrict__ ln_g,
    const float* __restrict__ ln_b, float* __restrict__ outp, int Nn)
{
  __shared__ alignas(16) unsigned short Als[16384];
  __shared__ alignas(16) unsigned short Bls[16384];
  const int tid = threadIdx.x;
  const int t = blockIdx.x & 1;
  const int m0 = (blockIdx.x >> 1) * 128;
  const int lane = tid & 63, w = tid >> 6;
  const int col = lane & 15, quad = lane >> 4;

  {  // stage A + B via async DMA (both images pre-swizzled)
    const unsigned short* Ab = gbuf + ((size_t)t * Nn + m0) * 128;
    const unsigned short* Bm = Wfb + (((size_t)(t * 4 + 3)) << 14);
    #pragma unroll
    for (int i = 0; i < 8; ++i) {
      int cc = w * 8 + i;
      gld16(&Als[cc * 512], Ab + (size_t)cc * 512 + lane * 8);  // may over-read tail (in ws)
      gld16(&Bls[cc * 512], Bm + cc * 512 + lane * 8);
    }
  }
  __syncthreads();

  floatx4 acc[2][8];
  #pragma unroll
  for (int mi = 0; mi < 2; ++mi)
    #pragma unroll
    for (int ni = 0; ni < 8; ++ni) acc[mi][ni] = (floatx4)(0.f);

  #pragma unroll
  for (int k0 = 0; k0 < 128; k0 += 32) {
    int gk = (k0 >> 3) + quad;
    short8 a0 = lds_frag(Als, w * 32 + col, gk);
    short8 a1 = lds_frag(Als, w * 32 + 16 + col, gk);
    #pragma unroll
    for (int ni = 0; ni < 8; ++ni) {
      short8 bf_ = lds_frag(Bls, ni * 16 + col, gk);
      acc[0][ni] = __builtin_amdgcn_mfma_f32_16x16x32_bf16(a0, bf_, acc[0][ni], 0, 0, 0);
      acc[1][ni] = __builtin_amdgcn_mfma_f32_16x16x32_bf16(a1, bf_, acc[1][ni], 0, 0, 0);
    }
  }

  const float* Bv = Bf + t * 512 + 3 * 128;
  float bias_n[8], g_n[8], b_n[8];
  #pragma unroll
  for (int ni = 0; ni < 8; ++ni) {
    bias_n[ni] = Bv[ni * 16 + col];
    g_n[ni]    = ln_g[ni * 16 + col];
    b_n[ni]    = ln_b[ni * 16 + col];
  }
  float sv = skip[t];
  float beta = 1.f / (1.f + __expf(-sv));
  const float* xt = x + (size_t)t * Nn * 128;
  float* op = outp + (size_t)t * Nn * 128;

  #pragma unroll
  for (int mi = 0; mi < 2; ++mi)
    #pragma unroll
    for (int reg = 0; reg < 4; ++reg) {
      int row = m0 + w * 32 + mi * 16 + quad * 4 + reg;
      if (row >= Nn) continue;            // uniform within the quad's 16 lanes
      const float* xr = xt + (size_t)row * 128;
      float vals[8], s = 0.f;
      #pragma unroll
      for (int ni = 0; ni < 8; ++ni) {
        float o = acc[mi][ni][reg] + bias_n[ni];
        float v = fmaxf(beta * o + (1.f - beta) * xr[ni * 16 + col], 0.f);
        vals[ni] = v; s += v;
      }
      #pragma unroll
      for (int off = 1; off < 16; off <<= 1) s += __shfl_xor(s, off, 64);
      float mu = s * 0.0078125f;
      float sq = 0.f;
      #pragma unroll
      for (int ni = 0; ni < 8; ++ni) { float d = vals[ni] - mu; sq += d * d; }
      #pragma unroll
      for (int off = 1; off < 16; off <<= 1) sq += __shfl_xor(sq, off, 64);
      float rstd = rsqrtf(sq * 0.0078125f + 1e-5f);
      float* orow = op + (size_t)row * 128 + col;
      #pragma unroll
      for (int ni = 0; ni < 8; ++ni)
        orow[ni * 16] = (vals[ni] - mu) * rstd * g_n[ni] + b_n[ni];
    }
}

// ---------------------------------------------------------------- launch
extern "C" void kernel_launch(void* const* d_in, const int* in_sizes, int n_in,
                              void* d_out, int out_size, void* d_ws, size_t ws_size,
                              hipStream_t stream) {
  const float* x     = (const float*)d_in[0];
  const float* k_w   = (const float*)d_in[1];
  const float* k_b   = (const float*)d_in[2];
  const float* q_w   = (const float*)d_in[3];
  const float* q_b   = (const float*)d_in[4];
  const float* v_w   = (const float*)d_in[5];
  const float* v_b   = (const float*)d_in[6];
  const float* a_w   = (const float*)d_in[7];
  const float* a_b   = (const float*)d_in[8];
  const float* skip  = (const float*)d_in[9];
  const float* a_rel = (const float*)d_in[10];
  const float* m_rel = (const float*)d_in[11];
  const float* p_rel = (const float*)d_in[12];
  const float* ln_g  = (const float*)d_in[13];
  const float* ln_b  = (const float*)d_in[14];
  const int* ei      = (const int*)d_in[15];
  float* out         = (float*)d_out;

  const int N = in_sizes[0] / 256;   // 50000 (divisible by 8 -> swizzle keys consistent)
  const int E = in_sizes[15] / 4;    // 500000

  // workspace carve-up (~119 MB)
  unsigned short* Wfb = (unsigned short*)d_ws;                 // 2*4*128*128 bf16
  float* Bf = (float*)(Wfb + 2 * 4 * 128 * 128);               // 2*4*128 f32
  unsigned short* qbuf = (unsigned short*)(Bf + 2 * 4 * 128);  // 2*N*128 bf16
  unsigned short* kvbuf = qbuf + (size_t)2 * N * 128;          // 2*N*256 bf16
  int* cnt  = (int*)(kvbuf + (size_t)2 * N * 256);             // 2*N int
  int* ebuf = cnt + (size_t)2 * N;                             // 2*N*EB_STRIDE int
  unsigned short* gbuf = (unsigned short*)(ebuf + (size_t)2 * N * EB_STRIDE); // 2*N*128 bf16

  fuse_weights<<<(2 * 4 * 128 * 128 + 255) / 256, 256, 0, stream>>>(
      k_w, k_b, q_w, q_b, v_w, v_b, a_w, a_b, a_rel, m_rel, p_rel, Wfb, Bf,
      cnt, 2 * N);

  int Mb = (N + 127) / 128;
  int Gg = Mb * 2;
  int Fb = 2 * ((E + 255) / 256);
  qkv_fill<<<Gg + Fb, 256, 0, stream>>>(
      x, Wfb, Bf, qbuf, kvbuf, ei, cnt, ebuf, N, E, Gg);

  gather_fused<<<(2 * N * 64 + 255) / 256, 256, 0, stream>>>(
      qbuf, kvbuf, cnt, ebuf, gbuf, N);

  gemm_ln<<<Gg, 256, 0, stream>>>(
      gbuf, Wfb, Bf, x, skip, ln_g, ln_b, out, N);
}

// Round 10
// 297.653 us; speedup vs baseline: 1.0144x; 1.0144x over previous
//
#include <hip/hip_runtime.h>
#include <math.h>

// HGT layer, MI355X. f32 inputs/outputs; bf16 intermediates (f32 accumulation).
// Round 10: revert GEMMs to round-7 structure (measured best: both <74us) --
// 128-row tiles, manual padded-LDS staging, packed kv uint writes. Keep the
// round-8 wins: fill_edges merged into qkv dispatch, cnt zeroing in fuse.
// Pipeline:
//  1) fuse_weights: fold a_rel/m_rel (+ p_rel/4 for khat) into weights; cnt=0
//  2) qkv_fill: blocks [0,Gg): QKV MFMA gemm (m order khat,vhat,q; packed kv);
//     blocks [Gg,..): bucket-append src per (dst_type,dst) (1 atomic/edge)
//  3) gather_fused: per-dst wave, 4 edges in flight (16-lane edge groups)
//  4) gemm_ln: o = gbuf @ a_w^T + a_b, fused skip/relu/LayerNorm -> f32 out

#define EB_STRIDE 40   // max in-degree bucket; Poisson(10): P(>=40) ~ 1e-13

typedef __attribute__((ext_vector_type(8))) short short8;
typedef __attribute__((ext_vector_type(4))) float floatx4;

__device__ __forceinline__ float bf2f(unsigned int bits16) {
  union { unsigned int i; float f; } u; u.i = bits16 << 16; return u.f;
}
__device__ __forceinline__ float bf2f_hi(unsigned int u) {
  union { unsigned int i; float f; } v; v.i = u & 0xffff0000u; return v.f;
}
__device__ __forceinline__ unsigned short f2bf(float f) {
  union { float ff; unsigned int i; } u; u.ff = f;
  unsigned int x = u.i;
  x += 0x7fffu + ((x >> 16) & 1u);
  return (unsigned short)(x >> 16);
}

// ---------------------------------------------------------------- fuse weights (+cnt zero)
// Wfb: [t][m][o][i] bf16, m: 0=q, 1=khat(a_rel-fused, *p_rel/4), 2=vhat, 3=a
__global__ void fuse_weights(
    const float* __restrict__ k_w, const float* __restrict__ k_b,
    const float* __restrict__ q_w, const float* __restrict__ q_b,
    const float* __restrict__ v_w, const float* __restrict__ v_b,
    const float* __restrict__ a_w, const float* __restrict__ a_b,
    const float* __restrict__ a_rel, const float* __restrict__ m_rel,
    const float* __restrict__ p_rel,
    unsigned short* __restrict__ Wfb, float* __restrict__ Bf,
    int* __restrict__ cnt, int nC)
{
  int tid = blockIdx.x * 256 + threadIdx.x;
  if (tid < nC) cnt[tid] = 0;
  if (tid >= 2 * 4 * 128 * 128) return;
  int t   = tid >> 16;
  int rem = tid & 65535;
  int m   = rem >> 14;
  int o   = (rem >> 7) & 127;
  int i   = rem & 127;
  float w, bias;
  if (m == 0) {
    w    = q_w[t * 16384 + o * 128 + i];
    bias = q_b[t * 128 + o];
  } else if (m == 3) {
    w    = a_w[t * 16384 + o * 128 + i];
    bias = a_b[t * 128 + o];
  } else {
    const float* bw  = (m == 1) ? k_w : v_w;
    const float* bb  = (m == 1) ? k_b : v_b;
    const float* rel = (m == 1) ? a_rel : m_rel;  // edge type e == source type t
    int h = o >> 4, eo = o & 15;
    float s = 0.f, sb = 0.f;
    #pragma unroll
    for (int d = 0; d < 16; ++d) {
      float r = rel[t * 2048 + h * 256 + d * 16 + eo];
      s  += bw[t * 16384 + (h * 16 + d) * 128 + i] * r;
      sb += bb[t * 128 + h * 16 + d] * r;
    }
    if (m == 1) {               // fold p_rel / sqrt(D) into khat
      float sc = p_rel[t * 8 + h] * 0.25f;
      s *= sc; sb *= sc;
    }
    w = s; bias = sb;
  }
  Wfb[tid] = f2bf(w);
  if (i == 0) Bf[t * 512 + m * 128 + o] = bias;
}

// ---------------------------------------------------------------- QKV gemm + edge fill
// blocks [0,Gg): gemm, 128-row tile (t = b&1, m0 = (b>>1)*128);
// blocks [Gg,+Fb): fill (e = f&1, 256 edges per block).
__global__ __launch_bounds__(256) void qkv_fill(
    const float* __restrict__ x, const unsigned short* __restrict__ Wfb,
    const float* __restrict__ Bf, unsigned short* __restrict__ qbuf,
    unsigned short* __restrict__ kvbuf,
    const int* __restrict__ ei, int* __restrict__ cnt, int* __restrict__ ebuf,
    int Nn, int E, int Gg)
{
  __shared__ alignas(16) unsigned short Als[128][136];
  __shared__ alignas(16) unsigned short Bls[128][136];
  const int b = blockIdx.x;
  const int tid = threadIdx.x;

  if (b >= Gg) {   // ---------------- edge-bucket fill portion
    int f = b - Gg;
    int e = f & 1;
    int i = (f >> 1) * 256 + tid;
    if (i < E) {
      int src = ei[(size_t)e * 2 * E + i];
      int dst = ei[(size_t)e * 2 * E + E + i];
      int bk = (1 - e) * Nn + dst;        // dst type dt = 1-e
      int pos = atomicAdd(&cnt[bk], 1);
      if (pos < EB_STRIDE) ebuf[(size_t)bk * EB_STRIDE + pos] = src;
    }
    return;
  }

  // ---------------- gemm portion (round-7 structure)
  const int t = b & 1;
  const int m0 = (b >> 1) * 128;
  const int lane = tid & 63, w = tid >> 6;
  const int col = lane & 15, quad = lane >> 4;
  const int morder[3] = {1, 2, 0};

  {  // stage A tile (f32 -> bf16)
    int r = tid & 127, h = tid >> 7;
    int gn = m0 + r;
    if (gn < Nn) {
      const float* ap = x + (size_t)t * Nn * 128 + (size_t)gn * 128 + h * 64;
      #pragma unroll
      for (int j = 0; j < 16; ++j) {
        float4 f = ((const float4*)ap)[j];
        ushort4 s;
        s.x = f2bf(f.x); s.y = f2bf(f.y); s.z = f2bf(f.z); s.w = f2bf(f.w);
        *(ushort4*)&Als[r][h * 64 + j * 4] = s;
      }
    } else {
      ushort4 z = make_ushort4(0, 0, 0, 0);
      #pragma unroll
      for (int j = 0; j < 16; ++j) *(ushort4*)&Als[r][h * 64 + j * 4] = z;
    }
  }

  float acc_k[2][8][4];   // stashed biased khat
  float bias_n[8];

  for (int mi_ = 0; mi_ < 3; ++mi_) {
    int m = morder[mi_];
    __syncthreads();   // A visible (first iter); prior B reads done before overwrite
    {  // stage B_m
      int r = tid & 127, h = tid >> 7;
      const unsigned short* wp = Wfb + (((size_t)(t * 4 + m)) << 14) + r * 128 + h * 64;
      #pragma unroll
      for (int j = 0; j < 8; ++j)
        *(uint4*)&Bls[r][h * 64 + j * 8] = ((const uint4*)wp)[j];
    }
    __syncthreads();

    floatx4 acc[2][8];
    #pragma unroll
    for (int mi = 0; mi < 2; ++mi)
      #pragma unroll
      for (int ni = 0; ni < 8; ++ni) acc[mi][ni] = (floatx4)(0.f);

    #pragma unroll
    for (int k0 = 0; k0 < 128; k0 += 32) {
      int kk = k0 + quad * 8;
      short8 a0 = *(const short8*)&Als[w * 32 + col][kk];
      short8 a1 = *(const short8*)&Als[w * 32 + 16 + col][kk];
      #pragma unroll
      for (int ni = 0; ni < 8; ++ni) {
        short8 bb = *(const short8*)&Bls[ni * 16 + col][kk];
        acc[0][ni] = __builtin_amdgcn_mfma_f32_16x16x32_bf16(a0, bb, acc[0][ni], 0, 0, 0);
        acc[1][ni] = __builtin_amdgcn_mfma_f32_16x16x32_bf16(a1, bb, acc[1][ni], 0, 0, 0);
      }
    }

    const float* Bv = Bf + t * 512 + m * 128;
    #pragma unroll
    for (int ni = 0; ni < 8; ++ni) bias_n[ni] = Bv[ni * 16 + col];

    if (m == 1) {
      // stash biased khat in registers; no global write
      #pragma unroll
      for (int mi = 0; mi < 2; ++mi)
        #pragma unroll
        for (int ni = 0; ni < 8; ++ni)
          #pragma unroll
          for (int reg = 0; reg < 4; ++reg)
            acc_k[mi][ni][reg] = acc[mi][ni][reg] + bias_n[ni];
    } else if (m == 2) {
      // write packed (khat, vhat) uint pairs: quad covers 64B contiguous
      unsigned int* kvp = (unsigned int*)kvbuf + ((size_t)t * Nn) * 128;
      #pragma unroll
      for (int mi = 0; mi < 2; ++mi)
        #pragma unroll
        for (int reg = 0; reg < 4; ++reg) {
          int row = m0 + w * 32 + mi * 16 + quad * 4 + reg;
          if (row >= Nn) continue;
          unsigned int* cp = kvp + (size_t)row * 128 + col;
          #pragma unroll
          for (int ni = 0; ni < 8; ++ni) {
            unsigned int kbits = f2bf(acc_k[mi][ni][reg]);
            unsigned int vbits = f2bf(acc[mi][ni][reg] + bias_n[ni]);
            cp[ni * 16] = (vbits << 16) | kbits;   // kv[2c]=khat, kv[2c+1]=vhat
          }
        }
    } else {
      #pragma unroll
      for (int mi = 0; mi < 2; ++mi)
        #pragma unroll
        for (int reg = 0; reg < 4; ++reg) {
          int row = m0 + w * 32 + mi * 16 + quad * 4 + reg;
          if (row >= Nn) continue;
          unsigned short* cp = qbuf + ((size_t)t * Nn + row) * 128 + col;
          #pragma unroll
          for (int ni = 0; ni < 8; ++ni)
            cp[ni * 16] = f2bf(acc[mi][ni][reg] + bias_n[ni]);
        }
    }
  }
}

// ---------------------------------------------------------------- fused gather
// one wave per dst node; 4 edges in flight (group g = lane>>4 owns edge j0+g,
// lane gl = lane&15 owns channels [8gl, 8gl+8) -> head gl>>1, partner gl^1).
__global__ __launch_bounds__(256) void gather_fused(
    const unsigned short* __restrict__ qbuf, const unsigned short* __restrict__ kvbuf,
    const int* __restrict__ cnt, const int* __restrict__ ebuf,
    unsigned short* __restrict__ gbuf, int N)
{
  int wid = (blockIdx.x * 256 + threadIdx.x) >> 6;   // bucket = dt*N + dst
  int l = threadIdx.x & 63;
  if (wid >= 2 * N) return;
  int dt = (wid >= N) ? 1 : 0;
  int e  = 1 - dt;                                   // source type
  int deg = cnt[wid]; if (deg > EB_STRIDE) deg = EB_STRIDE;
  int g = l >> 4, gl = l & 15;

  uint4 qr = *(const uint4*)(qbuf + (size_t)wid * 128 + 8 * gl);
  float qv[8];
  qv[0] = bf2f(qr.x & 0xffffu); qv[1] = bf2f(qr.x >> 16);
  qv[2] = bf2f(qr.y & 0xffffu); qv[3] = bf2f(qr.y >> 16);
  qv[4] = bf2f(qr.z & 0xffffu); qv[5] = bf2f(qr.z >> 16);
  qv[6] = bf2f(qr.w & 0xffffu); qv[7] = bf2f(qr.w >> 16);

  const unsigned short* kvbase = kvbuf + ((size_t)e * N) * 256;
  const int* eb = ebuf + (size_t)wid * EB_STRIDE;
  int mysrc = (l < deg) ? eb[l] : 0;

  float acc[8];
  #pragma unroll
  for (int c = 0; c < 8; ++c) acc[c] = 0.f;
  float den = 0.f;

  for (int j0 = 0; j0 < deg; j0 += 4) {
    int j = j0 + g;
    bool valid = j < deg;
    int src = __shfl(mysrc, valid ? j : 0, 64);
    const unsigned short* kv = kvbase + (size_t)src * 256 + 16 * gl;
    uint4 a = *(const uint4*)kv;        // channels 8gl+0..3 as (khat, vhat) pairs
    uint4 b = *(const uint4*)(kv + 8);  // channels 8gl+4..7
    float p;
    p = qv[0] * bf2f(a.x & 0xffffu);
    p = fmaf(qv[1], bf2f(a.y & 0xffffu), p);
    p = fmaf(qv[2], bf2f(a.z & 0xffffu), p);
    p = fmaf(qv[3], bf2f(a.w & 0xffffu), p);
    p = fmaf(qv[4], bf2f(b.x & 0xffffu), p);
    p = fmaf(qv[5], bf2f(b.y & 0xffffu), p);
    p = fmaf(qv[6], bf2f(b.z & 0xffffu), p);
    p = fmaf(qv[7], bf2f(b.w & 0xffffu), p);
    float pt = p + __shfl_xor(p, 1, 64);   // partner lane completes the 16-ch head dot
    float ex = valid ? __expf(pt) : 0.f;   // alpha scale folded into khat weights
    den += ex;
    acc[0] = fmaf(ex, bf2f_hi(a.x), acc[0]);
    acc[1] = fmaf(ex, bf2f_hi(a.y), acc[1]);
    acc[2] = fmaf(ex, bf2f_hi(a.z), acc[2]);
    acc[3] = fmaf(ex, bf2f_hi(a.w), acc[3]);
    acc[4] = fmaf(ex, bf2f_hi(b.x), acc[4]);
    acc[5] = fmaf(ex, bf2f_hi(b.y), acc[5]);
    acc[6] = fmaf(ex, bf2f_hi(b.z), acc[6]);
    acc[7] = fmaf(ex, bf2f_hi(b.w), acc[7]);
  }

  #pragma unroll
  for (int off = 16; off < 64; off <<= 1) {
    #pragma unroll
    for (int c = 0; c < 8; ++c) acc[c] += __shfl_xor(acc[c], off, 64);
    den += __shfl_xor(den, off, 64);
  }

  if (g == 0) {
    float rden = 1.f / (den + 1e-16f);
    unsigned short r[8];
    #pragma unroll
    for (int c = 0; c < 8; ++c) {
      float gg = acc[c] * rden;
      r[c] = f2bf(0.5f * gg * (1.f + erff(gg * 0.70710678118654752f)));
    }
    unsigned short* op = gbuf + (size_t)wid * 128 + 8 * gl;
    *(ushort4*)op       = make_ushort4(r[0], r[1], r[2], r[3]);
    *(ushort4*)(op + 4) = make_ushort4(r[4], r[5], r[6], r[7]);
  }
}

// ---------------------------------------------------------------- out GEMM + LN
// 128-row tile (t = b&1, m0 = (b>>1)*128). o = gbuf @ W^T + Bv; skip-gate +
// relu + LayerNorm fused; f32 out. Round-7 structure.
__global__ __launch_bounds__(256) void gemm_ln(
    const unsigned short* __restrict__ gbuf, const unsigned short* __restrict__ Wfb,
    const float* __restrict__ Bf, const float* __restrict__ x,
    const float* __restrict__ skip, const float* __restrict__ ln_g,
    const float* __restrict__ ln_b, float* __restrict__ outp, int Nn)
{
  __shared__ alignas(16) unsigned short Als[128][136];
  __shared__ alignas(16) unsigned short Bls[128][136];
  const int tid = threadIdx.x;
  const int t = blockIdx.x & 1;
  const int m0 = (blockIdx.x >> 1) * 128;
  const int lane = tid & 63, w = tid >> 6;
  const int col = lane & 15, quad = lane >> 4;

  {  // stage A (already bf16)
    int r = tid & 127, h = tid >> 7;
    int gn = m0 + r;
    if (gn < Nn) {
      const unsigned short* ap = gbuf + (size_t)t * Nn * 128 + (size_t)gn * 128 + h * 64;
      #pragma unroll
      for (int j = 0; j < 8; ++j)
        *(uint4*)&Als[r][h * 64 + j * 8] = ((const uint4*)ap)[j];
    } else {
      uint4 z = make_uint4(0, 0, 0, 0);
      #pragma unroll
      for (int j = 0; j < 8; ++j) *(uint4*)&Als[r][h * 64 + j * 8] = z;
    }
  }
  {  // stage B (weights m=3)
    int r = tid & 127, h = tid >> 7;
    const unsigned short* wp = Wfb + (((size_t)(t * 4 + 3)) << 14) + r * 128 + h * 64;
    #pragma unroll
    for (int j = 0; j < 8; ++j)
      *(uint4*)&Bls[r][h * 64 + j * 8] = ((const uint4*)wp)[j];
  }
  __syncthreads();

  floatx4 acc[2][8];
  #pragma unroll
  for (int mi = 0; mi < 2; ++mi)
    #pragma unroll
    for (int ni = 0; ni < 8; ++ni) acc[mi][ni] = (floatx4)(0.f);

  #pragma unroll
  for (int k0 = 0; k0 < 128; k0 += 32) {
    int kk = k0 + quad * 8;
    short8 a0 = *(const short8*)&Als[w * 32 + col][kk];
    short8 a1 = *(const short8*)&Als[w * 32 + 16 + col][kk];
    #pragma unroll
    for (int ni = 0; ni < 8; ++ni) {
      short8 bb = *(const short8*)&Bls[ni * 16 + col][kk];
      acc[0][ni] = __builtin_amdgcn_mfma_f32_16x16x32_bf16(a0, bb, acc[0][ni], 0, 0, 0);
      acc[1][ni] = __builtin_amdgcn_mfma_f32_16x16x32_bf16(a1, bb, acc[1][ni], 0, 0, 0);
    }
  }

  const float* Bv = Bf + t * 512 + 3 * 128;
  float bias_n[8], g_n[8], b_n[8];
  #pragma unroll
  for (int ni = 0; ni < 8; ++ni) {
    bias_n[ni] = Bv[ni * 16 + col];
    g_n[ni]    = ln_g[ni * 16 + col];
    b_n[ni]    = ln_b[ni * 16 + col];
  }
  float sv = skip[t];
  float beta = 1.f / (1.f + __expf(-sv));
  const float* xt = x + (size_t)t * Nn * 128;
  float* op = outp + (size_t)t * Nn * 128;

  #pragma unroll
  for (int mi = 0; mi < 2; ++mi)
    #pragma unroll
    for (int reg = 0; reg < 4; ++reg) {
      int row = m0 + w * 32 + mi * 16 + quad * 4 + reg;
      if (row >= Nn) continue;            // uniform within the quad's 16 lanes
      const float* xr = xt + (size_t)row * 128;
      float vals[8], s = 0.f;
      #pragma unroll
      for (int ni = 0; ni < 8; ++ni) {
        float o = acc[mi][ni][reg] + bias_n[ni];
        float v = fmaxf(beta * o + (1.f - beta) * xr[ni * 16 + col], 0.f);
        vals[ni] = v; s += v;
      }
      #pragma unroll
      for (int off = 1; off < 16; off <<= 1) s += __shfl_xor(s, off, 64);
      float mu = s * 0.0078125f;
      float sq = 0.f;
      #pragma unroll
      for (int ni = 0; ni < 8; ++ni) { float d = vals[ni] - mu; sq += d * d; }
      #pragma unroll
      for (int off = 1; off < 16; off <<= 1) sq += __shfl_xor(sq, off, 64);
      float rstd = rsqrtf(sq * 0.0078125f + 1e-5f);
      float* orow = op + (size_t)row * 128 + col;
      #pragma unroll
      for (int ni = 0; ni < 8; ++ni)
        orow[ni * 16] = (vals[ni] - mu) * rstd * g_n[ni] + b_n[ni];
    }
}

// ---------------------------------------------------------------- launch
extern "C" void kernel_launch(void* const* d_in, const int* in_sizes, int n_in,
                              void* d_out, int out_size, void* d_ws, size_t ws_size,
                              hipStream_t stream) {
  const float* x     = (const float*)d_in[0];
  const float* k_w   = (const float*)d_in[1];
  const float* k_b   = (const float*)d_in[2];
  const float* q_w   = (const float*)d_in[3];
  const float* q_b   = (const float*)d_in[4];
  const float* v_w   = (const float*)d_in[5];
  const float* v_b   = (const float*)d_in[6];
  const float* a_w   = (const float*)d_in[7];
  const float* a_b   = (const float*)d_in[8];
  const float* skip  = (const float*)d_in[9];
  const float* a_rel = (const float*)d_in[10];
  const float* m_rel = (const float*)d_in[11];
  const float* p_rel = (const float*)d_in[12];
  const float* ln_g  = (const float*)d_in[13];
  const float* ln_b  = (const float*)d_in[14];
  const int* ei      = (const int*)d_in[15];
  float* out         = (float*)d_out;

  const int N = in_sizes[0] / 256;   // 50000
  const int E = in_sizes[15] / 4;    // 500000

  // workspace carve-up (~119 MB)
  unsigned short* Wfb = (unsigned short*)d_ws;                 // 2*4*128*128 bf16
  float* Bf = (float*)(Wfb + 2 * 4 * 128 * 128);               // 2*4*128 f32
  unsigned short* qbuf = (unsigned short*)(Bf + 2 * 4 * 128);  // 2*N*128 bf16
  unsigned short* kvbuf = qbuf + (size_t)2 * N * 128;          // 2*N*256 bf16
  int* cnt  = (int*)(kvbuf + (size_t)2 * N * 256);             // 2*N int
  int* ebuf = cnt + (size_t)2 * N;                             // 2*N*EB_STRIDE int
  unsigned short* gbuf = (unsigned short*)(ebuf + (size_t)2 * N * EB_STRIDE); // 2*N*128 bf16

  fuse_weights<<<(2 * 4 * 128 * 128 + 255) / 256, 256, 0, stream>>>(
      k_w, k_b, q_w, q_b, v_w, v_b, a_w, a_b, a_rel, m_rel, p_rel, Wfb, Bf,
      cnt, 2 * N);

  int Mb = (N + 127) / 128;
  int Gg = Mb * 2;
  int Fb = 2 * ((E + 255) / 256);
  qkv_fill<<<Gg + Fb, 256, 0, stream>>>(
      x, Wfb, Bf, qbuf, kvbuf, ei, cnt, ebuf, N, E, Gg);

  gather_fused<<<(2 * N * 64 + 255) / 256, 256, 0, stream>>>(
      qbuf, kvbuf, cnt, ebuf, gbuf, N);

  gemm_ln<<<Gg, 256, 0, stream>>>(
      gbuf, Wfb, Bf, x, skip, ln_g, ln_b, out, N);
}